// Round 4
// baseline (913.609 us; speedup 1.0000x reference)
//
#include <hip/hip_runtime.h>
#include <hip/hip_bf16.h>
#include <math.h>

#define TOKENS 2048
#define HID 2048
#define FFN 1024
#define NEXP 16
#define NTOT 32
#define KSEL 4
#define RSCALE 2.5f

typedef __bf16 v8bf __attribute__((ext_vector_type(8)));
typedef float v4f __attribute__((ext_vector_type(4)));
typedef unsigned short u16x8v __attribute__((ext_vector_type(8)));

static __device__ __forceinline__ v8bf zero_v8bf() {
  u16x8v z = {0, 0, 0, 0, 0, 0, 0, 0};
  return __builtin_bit_cast(v8bf, z);
}

// Swizzled LDS addressing: row-major [rows][64] bf16 (128B rows, 8 chunks of
// 16B). Physical chunk = chunk ^ (row&7). Conflict-free (<=2-way, which is
// free) on both b128 staging writes and b128 fragment reads. Verified:
// SQ_LDS_BANK_CONFLICT == 0 in rounds 2-3.
static __device__ __forceinline__ int swz(int row, int chunk) {
  return (row << 6) + ((((unsigned)(chunk ^ row)) & 7u) << 3);
}

// ---------------------------------------------------------------------------
// Router: one block per token. Exact fp32 logits -> softmax -> bias-corrected
// top-4 (lowest-index tie-break), zero-expert folding, writes
// out = zero_total*x, bf16 hidden copy, per-expert (token,weight) lists.
// ---------------------------------------------------------------------------
__global__ __launch_bounds__(256) void router_kernel(
    const float* __restrict__ hidden, const float* __restrict__ rw,
    const float* __restrict__ bias, float* __restrict__ out,
    __bf16* __restrict__ hbf,
    int* __restrict__ counts, int* __restrict__ pair_token,
    float* __restrict__ pair_weight)
{
  const int t = blockIdx.x;
  const int tid = threadIdx.x;
  __shared__ float sh[HID];
  __shared__ float part[8][NTOT];
  __shared__ float s_zt;

  const float* hrow = hidden + (size_t)t * HID;
  for (int i = tid; i < HID / 4; i += 256)
    ((float4*)sh)[i] = ((const float4*)hrow)[i];
  __syncthreads();

  {
    const int base = tid * 8;
    v8bf v;
#pragma unroll
    for (int j = 0; j < 8; ++j) v[j] = (__bf16)sh[base + j];
    *(v8bf*)(hbf + (size_t)t * HID + base) = v;
  }

  {
    const int g = tid >> 5, e = tid & 31;
    const float* w = rw + (size_t)e * HID + g * 256;
    const float* hh = sh + g * 256;
    float acc = 0.f;
#pragma unroll 8
    for (int h = 0; h < 256; ++h) acc = fmaf(hh[h], w[h], acc);
    part[g][e] = acc;
  }
  __syncthreads();

  if (tid < 64) {
    const int lane = tid;
    float logit = -INFINITY;
    if (lane < NTOT) {
      float s = 0.f;
#pragma unroll
      for (int g = 0; g < 8; ++g) s += part[g][lane];
      logit = s;
    }
    float m = logit;
#pragma unroll
    for (int off = 32; off; off >>= 1) m = fmaxf(m, __shfl_xor(m, off));
    const float ex = (lane < NTOT) ? expf(logit - m) : 0.f;
    float sum = ex;
#pragma unroll
    for (int off = 32; off; off >>= 1) sum += __shfl_xor(sum, off);
    float sc = (lane < NTOT) ? (ex / sum + bias[lane]) : -INFINITY;

    float zt = 0.f;
#pragma unroll
    for (int it = 0; it < KSEL; ++it) {
      float v = sc; int vid = lane;
#pragma unroll
      for (int off = 32; off; off >>= 1) {
        const float ov = __shfl_xor(v, off);
        const int oid = __shfl_xor(vid, off);
        if (ov > v || (ov == v && oid < vid)) { v = ov; vid = oid; }
      }
      const float wv = v * RSCALE;
      if (vid >= NEXP) {
        zt += wv;
      } else if (lane == 0) {
        const int pos = atomicAdd(&counts[vid], 1);
        pair_token[vid * TOKENS + pos] = t;
        pair_weight[vid * TOKENS + pos] = wv;
      }
      if (lane == vid) sc = -INFINITY;
    }
    if (lane == 0) s_zt = zt;
  }
  __syncthreads();

  const float zt = s_zt;
  float* orow = out + (size_t)t * HID;
  for (int i = tid; i < HID / 4; i += 256) {
    float4 v = ((const float4*)sh)[i];
    v.x *= zt; v.y *= zt; v.z *= zt; v.w *= zt;
    ((float4*)orow)[i] = v;
  }
}

// ---------------------------------------------------------------------------
__global__ void scan_kernel(const int* __restrict__ counts,
                            int* __restrict__ offsets) {
  if (threadIdx.x == 0) {
    int acc = 0;
#pragma unroll
    for (int e = 0; e < NEXP; ++e) { offsets[e] = acc; acc += counts[e]; }
    offsets[NEXP] = acc;
  }
}

// ---------------------------------------------------------------------------
// GEMM1 (grouped): tile = 128 gathered rows x 32 f-cols (gate AND up), BK=64.
// Grid: (m-tile 16, f-tile 32, expert 16) -> ~1024 working blocks = 4/CU.
// LDS ~25KB/block. Wave grid 2x2: wr = M half (64 rows), wf = f half (16 f).
// Each wave computes gate+up for its f-half so swiglu is wave-local.
// ---------------------------------------------------------------------------
__global__ __launch_bounds__(256, 4) void gemm1_kernel(
    const __bf16* __restrict__ hbf, const float* __restrict__ w13,
    const int* __restrict__ counts, const int* __restrict__ offsets,
    const int* __restrict__ pair_token, const float* __restrict__ pair_weight,
    __bf16* __restrict__ act)
{
  const int e = blockIdx.z, mt = blockIdx.x, ft = blockIdx.y;
  const int cnt = counts[e];
  const int m0 = mt * 128;
  if (m0 >= cnt) return;
  const int obase = offsets[e];
  const int fbase = ft * 32;

  __shared__ __bf16 sA[128 * 64];   // [m][k]   16 KB
  __shared__ __bf16 sB[64 * 64];    // [f'][k]  8 KB; rows 0-31 gate, 32-63 up
  __shared__ int sTok[128];
  __shared__ float sW[128];

  const int tid = threadIdx.x;
  if (tid < 128) {
    const int m = m0 + tid;
    sTok[tid] = (m < cnt) ? pair_token[e * TOKENS + m] : -1;
    sW[tid] = (m < cnt) ? pair_weight[e * TOKENS + m] : 0.f;
  }
  __syncthreads();

  const int wid = tid >> 6, lane = tid & 63;
  const int wr = wid >> 1, wf = wid & 1;
  const int lrow = lane & 15, lq = lane >> 4;

  // A staging: 2 threads/row, 4 chunks (64B) each
  const int ar = tid >> 1, ac4 = (tid & 1) * 4;
  const int a_tok = sTok[ar];
  const __bf16* a_src =
      (a_tok >= 0) ? (hbf + (size_t)a_tok * HID + ac4 * 8) : nullptr;

  // B staging: lane -> (h = gate/up, f_off 0..31); 16 k-contiguous dwords per
  // thread (k = wid*16 + j). Each load instr = 2x128B contiguous segments.
  const int f_off = lane & 31, h = lane >> 5;
  const int brow = h * 32 + f_off;
  const float* b_ptr = w13 + (size_t)e * HID * (2 * FFN)
                     + (size_t)(wid * 16) * (2 * FFN) + h * FFN + fbase + f_off;

  v4f accg[4], accu[4];
#pragma unroll
  for (int mi = 0; mi < 4; ++mi) {
    v4f z = {0.f, 0.f, 0.f, 0.f};
    accg[mi] = z; accu[mi] = z;
  }

  for (int kt = 0; kt < HID; kt += 64) {
    // ---- stage A ----
    if (a_tok >= 0) {
      const v8bf* s = (const v8bf*)(a_src + kt);
#pragma unroll
      for (int c = 0; c < 4; ++c) *(v8bf*)&sA[swz(ar, ac4 + c)] = s[c];
    } else {
#pragma unroll
      for (int c = 0; c < 4; ++c) *(v8bf*)&sA[swz(ar, ac4 + c)] = zero_v8bf();
    }
    // ---- stage B (transposed, fp32 -> bf16) ----
    {
      const float* src = b_ptr + (size_t)kt * (2 * FFN);
      float pb[16];
#pragma unroll
      for (int j = 0; j < 16; ++j) pb[j] = src[(size_t)j * (2 * FFN)];
      v8bf v0, v1;
#pragma unroll
      for (int j = 0; j < 8; ++j) { v0[j] = (__bf16)pb[j]; v1[j] = (__bf16)pb[j + 8]; }
      *(v8bf*)&sB[swz(brow, wid * 2)] = v0;
      *(v8bf*)&sB[swz(brow, wid * 2 + 1)] = v1;
    }
    __syncthreads();

#pragma unroll
    for (int ks = 0; ks < 2; ++ks) {
      v8bf a[4];
#pragma unroll
      for (int mi = 0; mi < 4; ++mi)
        a[mi] = *(const v8bf*)&sA[swz(wr * 64 + mi * 16 + lrow, ks * 4 + lq)];
      const v8bf bg = *(const v8bf*)&sB[swz(wf * 16 + lrow, ks * 4 + lq)];
      const v8bf bu = *(const v8bf*)&sB[swz(32 + wf * 16 + lrow, ks * 4 + lq)];
#pragma unroll
      for (int mi = 0; mi < 4; ++mi) {
        accg[mi] = __builtin_amdgcn_mfma_f32_16x16x32_bf16(a[mi], bg, accg[mi], 0, 0, 0);
        accu[mi] = __builtin_amdgcn_mfma_f32_16x16x32_bf16(a[mi], bu, accu[mi], 0, 0, 0);
      }
    }
    __syncthreads();
  }

  // ---- epilogue: swiglu, fold routing weight, store act (bf16) ----
  const int f = fbase + wf * 16 + lrow;
#pragma unroll
  for (int mi = 0; mi < 4; ++mi) {
#pragma unroll
    for (int r = 0; r < 4; ++r) {
      const int lr = wr * 64 + mi * 16 + lq * 4 + r;
      const int m = m0 + lr;
      if (m < cnt) {
        const float g = accg[mi][r];
        const float u = accu[mi][r];
        const float sg = g / (1.f + __expf(-g));
        act[(size_t)(obase + m) * FFN + f] = (__bf16)(sg * u * sW[lr]);
      }
    }
  }
}

// ---------------------------------------------------------------------------
// GEMM2 (grouped): tile = 128 gathered rows x 64 n-cols, BK=64.
// Grid: (m-tile 16, n-tile 32, expert 16) -> ~1024 working blocks = 4/CU.
// Wave grid 2x2: wr = M half, wf = N half (32 cols, ni 0..1).
// atomicAdd into out (routing weight already folded into act).
// ---------------------------------------------------------------------------
__global__ __launch_bounds__(256, 4) void gemm2_kernel(
    const __bf16* __restrict__ act, const float* __restrict__ w2,
    const int* __restrict__ counts, const int* __restrict__ offsets,
    const int* __restrict__ pair_token, float* __restrict__ out)
{
  const int e = blockIdx.z, mt = blockIdx.x, nt = blockIdx.y;
  const int cnt = counts[e];
  const int m0 = mt * 128;
  if (m0 >= cnt) return;
  const int obase = offsets[e];
  const int n0 = nt * 64;

  __shared__ __bf16 sA[128 * 64];   // [m][k] 16 KB
  __shared__ __bf16 sB[64 * 64];    // [n][k] 8 KB
  __shared__ int sTok[128];

  const int tid = threadIdx.x;
  if (tid < 128) {
    const int m = m0 + tid;
    sTok[tid] = (m < cnt) ? pair_token[e * TOKENS + m] : -1;
  }
  __syncthreads();

  const int wid = tid >> 6, lane = tid & 63;
  const int wr = wid >> 1, wf = wid & 1;
  const int lrow = lane & 15, lq = lane >> 4;

  const int ar = tid >> 1, ac4 = (tid & 1) * 4;
  const bool avalid = (m0 + ar) < cnt;
  const __bf16* a_src =
      avalid ? (act + (size_t)(obase + m0 + ar) * FFN + ac4 * 8) : nullptr;

  // B staging: lane = n (0..63), 16 k-contiguous dwords (k = wid*16 + j);
  // each load instr = 256B contiguous.
  const float* b_ptr = w2 + (size_t)e * FFN * HID
                     + (size_t)(wid * 16) * HID + n0 + lane;

  v4f acc[4][2];
#pragma unroll
  for (int mi = 0; mi < 4; ++mi)
#pragma unroll
    for (int ni = 0; ni < 2; ++ni) {
      v4f z = {0.f, 0.f, 0.f, 0.f};
      acc[mi][ni] = z;
    }

  for (int kt = 0; kt < FFN; kt += 64) {
    // ---- stage A ----
    if (avalid) {
      const v8bf* s = (const v8bf*)(a_src + kt);
#pragma unroll
      for (int c = 0; c < 4; ++c) *(v8bf*)&sA[swz(ar, ac4 + c)] = s[c];
    } else {
#pragma unroll
      for (int c = 0; c < 4; ++c) *(v8bf*)&sA[swz(ar, ac4 + c)] = zero_v8bf();
    }
    // ---- stage B (transposed, fp32 -> bf16) ----
    {
      const float* src = b_ptr + (size_t)kt * HID;
      float pb[16];
#pragma unroll
      for (int j = 0; j < 16; ++j) pb[j] = src[(size_t)j * HID];
      v8bf v0, v1;
#pragma unroll
      for (int j = 0; j < 8; ++j) { v0[j] = (__bf16)pb[j]; v1[j] = (__bf16)pb[j + 8]; }
      *(v8bf*)&sB[swz(lane, wid * 2)] = v0;
      *(v8bf*)&sB[swz(lane, wid * 2 + 1)] = v1;
    }
    __syncthreads();

#pragma unroll
    for (int ks = 0; ks < 2; ++ks) {
      v8bf a[4], b[2];
#pragma unroll
      for (int mi = 0; mi < 4; ++mi)
        a[mi] = *(const v8bf*)&sA[swz(wr * 64 + mi * 16 + lrow, ks * 4 + lq)];
#pragma unroll
      for (int ni = 0; ni < 2; ++ni)
        b[ni] = *(const v8bf*)&sB[swz(wf * 32 + ni * 16 + lrow, ks * 4 + lq)];
#pragma unroll
      for (int mi = 0; mi < 4; ++mi)
#pragma unroll
        for (int ni = 0; ni < 2; ++ni)
          acc[mi][ni] = __builtin_amdgcn_mfma_f32_16x16x32_bf16(
              a[mi], b[ni], acc[mi][ni], 0, 0, 0);
    }
    __syncthreads();
  }

  // ---- epilogue: atomicAdd weighted expert output into out ----
#pragma unroll
  for (int mi = 0; mi < 4; ++mi) {
#pragma unroll
    for (int ni = 0; ni < 2; ++ni) {
#pragma unroll
      for (int r = 0; r < 4; ++r) {
        const int lr = wr * 64 + mi * 16 + lq * 4 + r;
        const int m = m0 + lr;
        if (m < cnt) {
          const int t = sTok[lr];
          const int n = n0 + wf * 32 + ni * 16 + lrow;
          atomicAdd(&out[(size_t)t * HID + n], acc[mi][ni][r]);
        }
      }
    }
  }
}

// ---------------------------------------------------------------------------
extern "C" void kernel_launch(void* const* d_in, const int* in_sizes, int n_in,
                              void* d_out, int out_size, void* d_ws, size_t ws_size,
                              hipStream_t stream) {
  const float* hidden = (const float*)d_in[0];
  const float* rw     = (const float*)d_in[1];
  const float* bias   = (const float*)d_in[2];
  const float* w13    = (const float*)d_in[3];
  const float* w2     = (const float*)d_in[4];
  float* out = (float*)d_out;

  char* ws = (char*)d_ws;
  int* counts = (int*)ws;
  int* offsets = (int*)(ws + 64);
  int* pair_token = (int*)(ws + 256);
  float* pair_weight = (float*)(ws + 256 + (size_t)NEXP * TOKENS * 4);
  __bf16* hbf = (__bf16*)(ws + 256 + 2 * (size_t)NEXP * TOKENS * 4);
  __bf16* act = hbf + (size_t)TOKENS * HID;

  hipMemsetAsync(counts, 0, 16 * sizeof(int), stream);
  router_kernel<<<TOKENS, 256, 0, stream>>>(hidden, rw, bias, out, hbf,
                                            counts, pair_token, pair_weight);
  scan_kernel<<<1, 64, 0, stream>>>(counts, offsets);
  gemm1_kernel<<<dim3(16, FFN / 32, NEXP), 256, 0, stream>>>(
      hbf, w13, counts, offsets, pair_token, pair_weight, act);
  gemm2_kernel<<<dim3(16, HID / 64, NEXP), 256, 0, stream>>>(
      act, w2, counts, offsets, pair_token, out);
}

// Round 5
// 588.977 us; speedup vs baseline: 1.5512x; 1.5512x over previous
//
#include <hip/hip_runtime.h>
#include <hip/hip_bf16.h>
#include <math.h>

#define TOKENS 2048
#define HID 2048
#define FFN 1024
#define NEXP 16
#define NTOT 32
#define KSEL 4
#define RSCALE 2.5f

typedef __bf16 v8bf __attribute__((ext_vector_type(8)));
typedef float v4f __attribute__((ext_vector_type(4)));
typedef unsigned short u16x8v __attribute__((ext_vector_type(8)));

static __device__ __forceinline__ v8bf zero_v8bf() {
  u16x8v z = {0, 0, 0, 0, 0, 0, 0, 0};
  return __builtin_bit_cast(v8bf, z);
}

// Swizzled LDS addressing: row-major [rows][64] bf16 (128B rows, 8 chunks of
// 16B). Physical chunk = chunk ^ (row&7). Verified conflict-free
// (SQ_LDS_BANK_CONFLICT == 0, rounds 2-4).
static __device__ __forceinline__ int swz(int row, int chunk) {
  return (row << 6) + ((((unsigned)(chunk ^ row)) & 7u) << 3);
}

// XCD-aware 1-D grid decode (round-4 lesson: working blocks with a sparse
// fastest-varying dim cluster onto 1-2 XCDs via lin%8 round-robin).
// lin = xcd + 8*(dense + ND*group_hi); group = group_hi*8 + xcd; group=(e,mt).
// -> working blocks spread over all XCDs AND all dense-tiles of one (e,mt)
// (which share the gathered A-panel) stay on one XCD's L2.
static __device__ __forceinline__ void decode_grid(int lin, int nd,
                                                   int& e, int& mt, int& d) {
  const int xcd = lin & 7;
  const int q = lin >> 3;
  d = q % nd;
  const int g = (q / nd) * 8 + xcd;
  mt = g & 15;
  e = g >> 4;
}

// ---------------------------------------------------------------------------
// Router: one block per token. Exact fp32 logits -> softmax -> bias-corrected
// top-4 (lowest-index tie-break), zero-expert folding, writes
// out = zero_total*x, bf16 hidden copy, per-expert (token,weight) lists.
// ---------------------------------------------------------------------------
__global__ __launch_bounds__(256) void router_kernel(
    const float* __restrict__ hidden, const float* __restrict__ rw,
    const float* __restrict__ bias, float* __restrict__ out,
    __bf16* __restrict__ hbf,
    int* __restrict__ counts, int* __restrict__ pair_token,
    float* __restrict__ pair_weight)
{
  const int t = blockIdx.x;
  const int tid = threadIdx.x;
  __shared__ float sh[HID];
  __shared__ float part[8][NTOT];
  __shared__ float s_zt;

  const float* hrow = hidden + (size_t)t * HID;
  for (int i = tid; i < HID / 4; i += 256)
    ((float4*)sh)[i] = ((const float4*)hrow)[i];
  __syncthreads();

  {
    const int base = tid * 8;
    v8bf v;
#pragma unroll
    for (int j = 0; j < 8; ++j) v[j] = (__bf16)sh[base + j];
    *(v8bf*)(hbf + (size_t)t * HID + base) = v;
  }

  {
    const int g = tid >> 5, e = tid & 31;
    const float* w = rw + (size_t)e * HID + g * 256;
    const float* hh = sh + g * 256;
    float acc = 0.f;
#pragma unroll 8
    for (int h = 0; h < 256; ++h) acc = fmaf(hh[h], w[h], acc);
    part[g][e] = acc;
  }
  __syncthreads();

  if (tid < 64) {
    const int lane = tid;
    float logit = -INFINITY;
    if (lane < NTOT) {
      float s = 0.f;
#pragma unroll
      for (int g = 0; g < 8; ++g) s += part[g][lane];
      logit = s;
    }
    float m = logit;
#pragma unroll
    for (int off = 32; off; off >>= 1) m = fmaxf(m, __shfl_xor(m, off));
    const float ex = (lane < NTOT) ? expf(logit - m) : 0.f;
    float sum = ex;
#pragma unroll
    for (int off = 32; off; off >>= 1) sum += __shfl_xor(sum, off);
    float sc = (lane < NTOT) ? (ex / sum + bias[lane]) : -INFINITY;

    float zt = 0.f;
#pragma unroll
    for (int it = 0; it < KSEL; ++it) {
      float v = sc; int vid = lane;
#pragma unroll
      for (int off = 32; off; off >>= 1) {
        const float ov = __shfl_xor(v, off);
        const int oid = __shfl_xor(vid, off);
        if (ov > v || (ov == v && oid < vid)) { v = ov; vid = oid; }
      }
      const float wv = v * RSCALE;
      if (vid >= NEXP) {
        zt += wv;
      } else if (lane == 0) {
        const int pos = atomicAdd(&counts[vid], 1);
        pair_token[vid * TOKENS + pos] = t;
        pair_weight[vid * TOKENS + pos] = wv;
      }
      if (lane == vid) sc = -INFINITY;
    }
    if (lane == 0) s_zt = zt;
  }
  __syncthreads();

  const float zt = s_zt;
  float* orow = out + (size_t)t * HID;
  for (int i = tid; i < HID / 4; i += 256) {
    float4 v = ((const float4*)sh)[i];
    v.x *= zt; v.y *= zt; v.z *= zt; v.w *= zt;
    ((float4*)orow)[i] = v;
  }
}

// ---------------------------------------------------------------------------
__global__ void scan_kernel(const int* __restrict__ counts,
                            int* __restrict__ offsets) {
  if (threadIdx.x == 0) {
    int acc = 0;
#pragma unroll
    for (int e = 0; e < NEXP; ++e) { offsets[e] = acc; acc += counts[e]; }
    offsets[NEXP] = acc;
  }
}

// ---------------------------------------------------------------------------
// GEMM1 (grouped): tile = 128 gathered rows x 32 f-cols (gate AND up), BK=64.
// 1-D grid, XCD-aware decode (dense dim = ft, 32 tiles). ~1024 working
// blocks spread 4/CU. LDS ~25.6KB. Waves 2x2: wr = M half, wf = f half.
// ---------------------------------------------------------------------------
__global__ __launch_bounds__(256, 4) void gemm1_kernel(
    const __bf16* __restrict__ hbf, const float* __restrict__ w13,
    const int* __restrict__ counts, const int* __restrict__ offsets,
    const int* __restrict__ pair_token, const float* __restrict__ pair_weight,
    __bf16* __restrict__ act)
{
  int e, mt, ft;
  decode_grid(blockIdx.x, FFN / 32, e, mt, ft);
  const int cnt = counts[e];
  const int m0 = mt * 128;
  if (m0 >= cnt) return;
  const int obase = offsets[e];
  const int fbase = ft * 32;

  __shared__ __bf16 sA[128 * 64];   // [m][k]   16 KB
  __shared__ __bf16 sB[64 * 64];    // [f'][k]  8 KB; rows 0-31 gate, 32-63 up
  __shared__ int sTok[128];
  __shared__ float sW[128];

  const int tid = threadIdx.x;
  if (tid < 128) {
    const int m = m0 + tid;
    sTok[tid] = (m < cnt) ? pair_token[e * TOKENS + m] : -1;
    sW[tid] = (m < cnt) ? pair_weight[e * TOKENS + m] : 0.f;
  }
  __syncthreads();

  const int wid = tid >> 6, lane = tid & 63;
  const int wr = wid >> 1, wf = wid & 1;
  const int lrow = lane & 15, lq = lane >> 4;

  // A staging: 2 threads/row, 4 chunks (64B) each
  const int ar = tid >> 1, ac4 = (tid & 1) * 4;
  const int a_tok = sTok[ar];
  const __bf16* a_src =
      (a_tok >= 0) ? (hbf + (size_t)a_tok * HID + ac4 * 8) : nullptr;

  // B staging: lane -> (h = gate/up, f_off 0..31); 16 k-strided dwords per
  // thread (k = wid*16 + j). Per instr: 2x128B contiguous segments per wave.
  const int f_off = lane & 31, h = lane >> 5;
  const int brow = h * 32 + f_off;
  const float* b_ptr = w13 + (size_t)e * HID * (2 * FFN)
                     + (size_t)(wid * 16) * (2 * FFN) + h * FFN + fbase + f_off;

  v4f accg[4], accu[4];
#pragma unroll
  for (int mi = 0; mi < 4; ++mi) {
    v4f z = {0.f, 0.f, 0.f, 0.f};
    accg[mi] = z; accu[mi] = z;
  }

  for (int kt = 0; kt < HID; kt += 64) {
    // ---- stage A ----
    if (a_tok >= 0) {
      const v8bf* s = (const v8bf*)(a_src + kt);
#pragma unroll
      for (int c = 0; c < 4; ++c) *(v8bf*)&sA[swz(ar, ac4 + c)] = s[c];
    } else {
#pragma unroll
      for (int c = 0; c < 4; ++c) *(v8bf*)&sA[swz(ar, ac4 + c)] = zero_v8bf();
    }
    // ---- stage B (transposed, fp32 -> bf16) ----
    {
      const float* src = b_ptr + (size_t)kt * (2 * FFN);
      float pb[16];
#pragma unroll
      for (int j = 0; j < 16; ++j) pb[j] = src[(size_t)j * (2 * FFN)];
      v8bf v0, v1;
#pragma unroll
      for (int j = 0; j < 8; ++j) { v0[j] = (__bf16)pb[j]; v1[j] = (__bf16)pb[j + 8]; }
      *(v8bf*)&sB[swz(brow, wid * 2)] = v0;
      *(v8bf*)&sB[swz(brow, wid * 2 + 1)] = v1;
    }
    __syncthreads();

#pragma unroll
    for (int ks = 0; ks < 2; ++ks) {
      v8bf a[4];
#pragma unroll
      for (int mi = 0; mi < 4; ++mi)
        a[mi] = *(const v8bf*)&sA[swz(wr * 64 + mi * 16 + lrow, ks * 4 + lq)];
      const v8bf bg = *(const v8bf*)&sB[swz(wf * 16 + lrow, ks * 4 + lq)];
      const v8bf bu = *(const v8bf*)&sB[swz(32 + wf * 16 + lrow, ks * 4 + lq)];
#pragma unroll
      for (int mi = 0; mi < 4; ++mi) {
        accg[mi] = __builtin_amdgcn_mfma_f32_16x16x32_bf16(a[mi], bg, accg[mi], 0, 0, 0);
        accu[mi] = __builtin_amdgcn_mfma_f32_16x16x32_bf16(a[mi], bu, accu[mi], 0, 0, 0);
      }
    }
    __syncthreads();
  }

  // ---- epilogue: swiglu, fold routing weight, store act (bf16) ----
  const int f = fbase + wf * 16 + lrow;
#pragma unroll
  for (int mi = 0; mi < 4; ++mi) {
#pragma unroll
    for (int r = 0; r < 4; ++r) {
      const int lr = wr * 64 + mi * 16 + lq * 4 + r;
      const int m = m0 + lr;
      if (m < cnt) {
        const float g = accg[mi][r];
        const float u = accu[mi][r];
        const float sg = g / (1.f + __expf(-g));
        act[(size_t)(obase + m) * FFN + f] = (__bf16)(sg * u * sW[lr]);
      }
    }
  }
}

// ---------------------------------------------------------------------------
// GEMM2 (grouped): tile = 128 gathered rows x 64 n-cols, BK=64.
// 1-D grid, XCD-aware decode (dense dim = nt, 32 tiles). atomicAdd into out.
// ---------------------------------------------------------------------------
__global__ __launch_bounds__(256, 4) void gemm2_kernel(
    const __bf16* __restrict__ act, const float* __restrict__ w2,
    const int* __restrict__ counts, const int* __restrict__ offsets,
    const int* __restrict__ pair_token, float* __restrict__ out)
{
  int e, mt, nt;
  decode_grid(blockIdx.x, HID / 64, e, mt, nt);
  const int cnt = counts[e];
  const int m0 = mt * 128;
  if (m0 >= cnt) return;
  const int obase = offsets[e];
  const int n0 = nt * 64;

  __shared__ __bf16 sA[128 * 64];   // [m][k] 16 KB
  __shared__ __bf16 sB[64 * 64];    // [n][k] 8 KB
  __shared__ int sTok[128];

  const int tid = threadIdx.x;
  if (tid < 128) {
    const int m = m0 + tid;
    sTok[tid] = (m < cnt) ? pair_token[e * TOKENS + m] : -1;
  }
  __syncthreads();

  const int wid = tid >> 6, lane = tid & 63;
  const int wr = wid >> 1, wf = wid & 1;
  const int lrow = lane & 15, lq = lane >> 4;

  const int ar = tid >> 1, ac4 = (tid & 1) * 4;
  const bool avalid = (m0 + ar) < cnt;
  const __bf16* a_src =
      avalid ? (act + (size_t)(obase + m0 + ar) * FFN + ac4 * 8) : nullptr;

  // B staging: lane = n (0..63), 16 k-strided dwords (k = wid*16 + j);
  // per instr: 256B contiguous per wave.
  const float* b_ptr = w2 + (size_t)e * FFN * HID
                     + (size_t)(wid * 16) * HID + n0 + lane;

  v4f acc[4][2];
#pragma unroll
  for (int mi = 0; mi < 4; ++mi)
#pragma unroll
    for (int ni = 0; ni < 2; ++ni) {
      v4f z = {0.f, 0.f, 0.f, 0.f};
      acc[mi][ni] = z;
    }

  for (int kt = 0; kt < FFN; kt += 64) {
    // ---- stage A ----
    if (avalid) {
      const v8bf* s = (const v8bf*)(a_src + kt);
#pragma unroll
      for (int c = 0; c < 4; ++c) *(v8bf*)&sA[swz(ar, ac4 + c)] = s[c];
    } else {
#pragma unroll
      for (int c = 0; c < 4; ++c) *(v8bf*)&sA[swz(ar, ac4 + c)] = zero_v8bf();
    }
    // ---- stage B (transposed, fp32 -> bf16) ----
    {
      const float* src = b_ptr + (size_t)kt * HID;
      float pb[16];
#pragma unroll
      for (int j = 0; j < 16; ++j) pb[j] = src[(size_t)j * HID];
      v8bf v0, v1;
#pragma unroll
      for (int j = 0; j < 8; ++j) { v0[j] = (__bf16)pb[j]; v1[j] = (__bf16)pb[j + 8]; }
      *(v8bf*)&sB[swz(lane, wid * 2)] = v0;
      *(v8bf*)&sB[swz(lane, wid * 2 + 1)] = v1;
    }
    __syncthreads();

#pragma unroll
    for (int ks = 0; ks < 2; ++ks) {
      v8bf a[4], b[2];
#pragma unroll
      for (int mi = 0; mi < 4; ++mi)
        a[mi] = *(const v8bf*)&sA[swz(wr * 64 + mi * 16 + lrow, ks * 4 + lq)];
#pragma unroll
      for (int ni = 0; ni < 2; ++ni)
        b[ni] = *(const v8bf*)&sB[swz(wf * 32 + ni * 16 + lrow, ks * 4 + lq)];
#pragma unroll
      for (int mi = 0; mi < 4; ++mi)
#pragma unroll
        for (int ni = 0; ni < 2; ++ni)
          acc[mi][ni] = __builtin_amdgcn_mfma_f32_16x16x32_bf16(
              a[mi], b[ni], acc[mi][ni], 0, 0, 0);
    }
    __syncthreads();
  }

  // ---- epilogue: atomicAdd weighted expert output into out ----
#pragma unroll
  for (int mi = 0; mi < 4; ++mi) {
#pragma unroll
    for (int ni = 0; ni < 2; ++ni) {
#pragma unroll
      for (int r = 0; r < 4; ++r) {
        const int lr = wr * 64 + mi * 16 + lq * 4 + r;
        const int m = m0 + lr;
        if (m < cnt) {
          const int t = sTok[lr];
          const int n = n0 + wf * 32 + ni * 16 + lrow;
          atomicAdd(&out[(size_t)t * HID + n], acc[mi][ni][r]);
        }
      }
    }
  }
}

// ---------------------------------------------------------------------------
extern "C" void kernel_launch(void* const* d_in, const int* in_sizes, int n_in,
                              void* d_out, int out_size, void* d_ws, size_t ws_size,
                              hipStream_t stream) {
  const float* hidden = (const float*)d_in[0];
  const float* rw     = (const float*)d_in[1];
  const float* bias   = (const float*)d_in[2];
  const float* w13    = (const float*)d_in[3];
  const float* w2     = (const float*)d_in[4];
  float* out = (float*)d_out;

  char* ws = (char*)d_ws;
  int* counts = (int*)ws;
  int* offsets = (int*)(ws + 64);
  int* pair_token = (int*)(ws + 256);
  float* pair_weight = (float*)(ws + 256 + (size_t)NEXP * TOKENS * 4);
  __bf16* hbf = (__bf16*)(ws + 256 + 2 * (size_t)NEXP * TOKENS * 4);
  __bf16* act = hbf + (size_t)TOKENS * HID;

  hipMemsetAsync(counts, 0, 16 * sizeof(int), stream);
  router_kernel<<<TOKENS, 256, 0, stream>>>(hidden, rw, bias, out, hbf,
                                            counts, pair_token, pair_weight);
  scan_kernel<<<1, 64, 0, stream>>>(counts, offsets);
  // 1-D grids: 16 experts x 16 m-tiles x 32 dense tiles = 8192 blocks
  gemm1_kernel<<<NEXP * 16 * (FFN / 32), 256, 0, stream>>>(
      hbf, w13, counts, offsets, pair_token, pair_weight, act);
  gemm2_kernel<<<NEXP * 16 * (HID / 64), 256, 0, stream>>>(
      act, w2, counts, offsets, pair_token, out);
}

// Round 6
// 347.366 us; speedup vs baseline: 2.6301x; 1.6956x over previous
//
#include <hip/hip_runtime.h>
#include <hip/hip_bf16.h>
#include <math.h>

#define TOKENS 2048
#define HID 2048
#define FFN 1024
#define NEXP 16
#define NTOT 32
#define KSEL 4
#define RSCALE 2.5f

typedef __bf16 v8bf __attribute__((ext_vector_type(8)));
typedef float v4f __attribute__((ext_vector_type(4)));
typedef unsigned short u16x8v __attribute__((ext_vector_type(8)));

static __device__ __forceinline__ v8bf zero_v8bf() {
  u16x8v z = {0, 0, 0, 0, 0, 0, 0, 0};
  return __builtin_bit_cast(v8bf, z);
}

// Swizzled LDS addressing: row-major [rows][64] bf16 (128B rows, 8 chunks of
// 16B). Physical chunk = chunk ^ (row&7). Verified conflict-free
// (SQ_LDS_BANK_CONFLICT == 0, rounds 2-5).
static __device__ __forceinline__ int swz(int row, int chunk) {
  return (row << 6) + ((((unsigned)(chunk ^ row)) & 7u) << 3);
}

// ---------------------------------------------------------------------------
// Router: one block per token. Exact fp32 logits -> softmax -> bias-corrected
// top-4 (lowest-index tie-break), zero-expert folding, writes
// out = zero_total*x, bf16 hidden copy, per-expert (token,weight) lists.
// ---------------------------------------------------------------------------
__global__ __launch_bounds__(256) void router_kernel(
    const float* __restrict__ hidden, const float* __restrict__ rw,
    const float* __restrict__ bias, float* __restrict__ out,
    __bf16* __restrict__ hbf,
    int* __restrict__ counts, int* __restrict__ pair_token,
    float* __restrict__ pair_weight)
{
  const int t = blockIdx.x;
  const int tid = threadIdx.x;
  __shared__ float sh[HID];
  __shared__ float part[8][NTOT];
  __shared__ float s_zt;

  const float* hrow = hidden + (size_t)t * HID;
  for (int i = tid; i < HID / 4; i += 256)
    ((float4*)sh)[i] = ((const float4*)hrow)[i];
  __syncthreads();

  {
    const int base = tid * 8;
    v8bf v;
#pragma unroll
    for (int j = 0; j < 8; ++j) v[j] = (__bf16)sh[base + j];
    *(v8bf*)(hbf + (size_t)t * HID + base) = v;
  }

  {
    const int g = tid >> 5, e = tid & 31;
    const float* w = rw + (size_t)e * HID + g * 256;
    const float* hh = sh + g * 256;
    float acc = 0.f;
#pragma unroll 8
    for (int h = 0; h < 256; ++h) acc = fmaf(hh[h], w[h], acc);
    part[g][e] = acc;
  }
  __syncthreads();

  if (tid < 64) {
    const int lane = tid;
    float logit = -INFINITY;
    if (lane < NTOT) {
      float s = 0.f;
#pragma unroll
      for (int g = 0; g < 8; ++g) s += part[g][lane];
      logit = s;
    }
    float m = logit;
#pragma unroll
    for (int off = 32; off; off >>= 1) m = fmaxf(m, __shfl_xor(m, off));
    const float ex = (lane < NTOT) ? expf(logit - m) : 0.f;
    float sum = ex;
#pragma unroll
    for (int off = 32; off; off >>= 1) sum += __shfl_xor(sum, off);
    float sc = (lane < NTOT) ? (ex / sum + bias[lane]) : -INFINITY;

    float zt = 0.f;
#pragma unroll
    for (int it = 0; it < KSEL; ++it) {
      float v = sc; int vid = lane;
#pragma unroll
      for (int off = 32; off; off >>= 1) {
        const float ov = __shfl_xor(v, off);
        const int oid = __shfl_xor(vid, off);
        if (ov > v || (ov == v && oid < vid)) { v = ov; vid = oid; }
      }
      const float wv = v * RSCALE;
      if (vid >= NEXP) {
        zt += wv;
      } else if (lane == 0) {
        const int pos = atomicAdd(&counts[vid], 1);
        pair_token[vid * TOKENS + pos] = t;
        pair_weight[vid * TOKENS + pos] = wv;
      }
      if (lane == vid) sc = -INFINITY;
    }
    if (lane == 0) s_zt = zt;
  }
  __syncthreads();

  const float zt = s_zt;
  float* orow = out + (size_t)t * HID;
  for (int i = tid; i < HID / 4; i += 256) {
    float4 v = ((const float4*)sh)[i];
    v.x *= zt; v.y *= zt; v.z *= zt; v.w *= zt;
    ((float4*)orow)[i] = v;
  }
}

// ---------------------------------------------------------------------------
__global__ void scan_kernel(const int* __restrict__ counts,
                            int* __restrict__ offsets) {
  if (threadIdx.x == 0) {
    int acc = 0;
#pragma unroll
    for (int e = 0; e < NEXP; ++e) { offsets[e] = acc; acc += counts[e]; }
    offsets[NEXP] = acc;
  }
}

// ---------------------------------------------------------------------------
// GEMM1 (grouped): tile = 64 gathered rows x 64 f-cols (gate AND up), BK=64.
// 1-D grid, XCD decode with group=(e,ft) pinned to one XCD, dense=mt:
// the ~4 m-tiles sharing a B-strip are co-resident on one XCD -> w13 is
// fetched from HBM once and L2-shared (round-5 lesson: share the BIG operand).
// Working blocks ~1024 = 4/CU. LDS ~24.5 KB.
// ---------------------------------------------------------------------------
__global__ __launch_bounds__(256, 4) void gemm1_kernel(
    const __bf16* __restrict__ hbf, const float* __restrict__ w13,
    const int* __restrict__ counts, const int* __restrict__ offsets,
    const int* __restrict__ pair_token, const float* __restrict__ pair_weight,
    __bf16* __restrict__ act)
{
  const int lin = blockIdx.x;
  const int xcd = lin & 7;
  const int q = lin >> 3;
  const int mt = q & 31;                 // dense: 32 m-tiles of 64 rows
  const int g = (q >> 5) * 8 + xcd;      // group 0..255 = (e, ft)
  const int ft = g & 15;
  const int e = g >> 4;

  const int cnt = counts[e];
  const int m0 = mt * 64;
  if (m0 >= cnt) return;
  const int obase = offsets[e];
  const int fbase = ft * 64;

  __shared__ __bf16 sA[64 * 64];    // [m][k]   8 KB
  __shared__ __bf16 sB[128 * 64];   // [f'][k] 16 KB; rows 0-63 gate, 64-127 up
  __shared__ int sTok[64];
  __shared__ float sW[64];

  const int tid = threadIdx.x;
  if (tid < 64) {
    const int m = m0 + tid;
    sTok[tid] = (m < cnt) ? pair_token[e * TOKENS + m] : -1;
    sW[tid] = (m < cnt) ? pair_weight[e * TOKENS + m] : 0.f;
  }
  __syncthreads();

  const int wid = tid >> 6, lane = tid & 63;
  const int wr = wid >> 1, wf = wid & 1;
  const int lrow = lane & 15, lq = lane >> 4;

  // A staging: 4 threads/row, 2 chunks (32B) each
  const int ar = tid >> 2, ac = (tid & 3) * 2;
  const int a_tok = sTok[ar];
  const __bf16* a_src =
      (a_tok >= 0) ? (hbf + (size_t)a_tok * HID + ac * 8) : nullptr;

  // B staging: thread -> (h=gate/up, f_off 0..63 via wid-bit1, k-half via
  // wid-bit0), 32 k-strided dwords. Per instr: 2x128B contiguous segments.
  const int h = lane >> 5;
  const int f_off = (wid >> 1) * 32 + (lane & 31);
  const int brow = h * 64 + f_off;
  const int bc0 = (wid & 1) * 4;
  const float* b_ptr = w13 + (size_t)e * HID * (2 * FFN)
                     + (size_t)((wid & 1) * 32) * (2 * FFN)
                     + h * FFN + fbase + f_off;

  v4f accg[2][2], accu[2][2];
#pragma unroll
  for (int mi = 0; mi < 2; ++mi)
#pragma unroll
    for (int fi = 0; fi < 2; ++fi) {
      v4f z = {0.f, 0.f, 0.f, 0.f};
      accg[mi][fi] = z; accu[mi][fi] = z;
    }

  for (int kt = 0; kt < HID; kt += 64) {
    // ---- stage A ----
    if (a_tok >= 0) {
      const v8bf* s = (const v8bf*)(a_src + kt);
      *(v8bf*)&sA[swz(ar, ac)] = s[0];
      *(v8bf*)&sA[swz(ar, ac + 1)] = s[1];
    } else {
      *(v8bf*)&sA[swz(ar, ac)] = zero_v8bf();
      *(v8bf*)&sA[swz(ar, ac + 1)] = zero_v8bf();
    }
    // ---- stage B (transposed, fp32 -> bf16) ----
    {
      const float* src = b_ptr + (size_t)kt * (2 * FFN);
      float pb[32];
#pragma unroll
      for (int j = 0; j < 32; ++j) pb[j] = src[(size_t)j * (2 * FFN)];
#pragma unroll
      for (int c = 0; c < 4; ++c) {
        v8bf v;
#pragma unroll
        for (int j = 0; j < 8; ++j) v[j] = (__bf16)pb[c * 8 + j];
        *(v8bf*)&sB[swz(brow, bc0 + c)] = v;
      }
    }
    __syncthreads();

#pragma unroll
    for (int ks = 0; ks < 2; ++ks) {
      v8bf a[2], bg[2], bu[2];
#pragma unroll
      for (int mi = 0; mi < 2; ++mi)
        a[mi] = *(const v8bf*)&sA[swz(wr * 32 + mi * 16 + lrow, ks * 4 + lq)];
#pragma unroll
      for (int fi = 0; fi < 2; ++fi) {
        bg[fi] = *(const v8bf*)&sB[swz(wf * 32 + fi * 16 + lrow, ks * 4 + lq)];
        bu[fi] = *(const v8bf*)&sB[swz(64 + wf * 32 + fi * 16 + lrow, ks * 4 + lq)];
      }
#pragma unroll
      for (int mi = 0; mi < 2; ++mi)
#pragma unroll
        for (int fi = 0; fi < 2; ++fi) {
          accg[mi][fi] = __builtin_amdgcn_mfma_f32_16x16x32_bf16(
              a[mi], bg[fi], accg[mi][fi], 0, 0, 0);
          accu[mi][fi] = __builtin_amdgcn_mfma_f32_16x16x32_bf16(
              a[mi], bu[fi], accu[mi][fi], 0, 0, 0);
        }
    }
    __syncthreads();
  }

  // ---- epilogue: swiglu, fold routing weight, store act (bf16) ----
#pragma unroll
  for (int mi = 0; mi < 2; ++mi) {
#pragma unroll
    for (int fi = 0; fi < 2; ++fi) {
      const int f = fbase + wf * 32 + fi * 16 + lrow;
#pragma unroll
      for (int r = 0; r < 4; ++r) {
        const int lr = wr * 32 + mi * 16 + lq * 4 + r;
        const int m = m0 + lr;
        if (m < cnt) {
          const float gg = accg[mi][fi][r];
          const float uu = accu[mi][fi][r];
          const float sg = gg / (1.f + __expf(-gg));
          act[(size_t)(obase + m) * FFN + f] = (__bf16)(sg * uu * sW[lr]);
        }
      }
    }
  }
}

// ---------------------------------------------------------------------------
// GEMM2 (grouped): tile = 64 gathered rows x 64 n-cols, BK=64.
// Same decode philosophy: group=(e,nt) on one XCD, dense=mt -> w2 L2-shared.
// Working blocks ~2048 = 8/CU. atomicAdd into out.
// ---------------------------------------------------------------------------
__global__ __launch_bounds__(256, 4) void gemm2_kernel(
    const __bf16* __restrict__ act, const float* __restrict__ w2,
    const int* __restrict__ counts, const int* __restrict__ offsets,
    const int* __restrict__ pair_token, float* __restrict__ out)
{
  const int lin = blockIdx.x;
  const int xcd = lin & 7;
  const int q = lin >> 3;
  const int mt = q & 31;                 // dense: 32 m-tiles of 64 rows
  const int g = (q >> 5) * 8 + xcd;      // group 0..511 = (e, nt)
  const int nt = g & 31;
  const int e = g >> 5;

  const int cnt = counts[e];
  const int m0 = mt * 64;
  if (m0 >= cnt) return;
  const int obase = offsets[e];
  const int n0 = nt * 64;

  __shared__ __bf16 sA[64 * 64];    // [m][k] 8 KB
  __shared__ __bf16 sB[64 * 64];    // [n][k] 8 KB
  __shared__ int sTok[64];

  const int tid = threadIdx.x;
  if (tid < 64) {
    const int m = m0 + tid;
    sTok[tid] = (m < cnt) ? pair_token[e * TOKENS + m] : -1;
  }
  __syncthreads();

  const int wid = tid >> 6, lane = tid & 63;
  const int wr = wid >> 1, wf = wid & 1;
  const int lrow = lane & 15, lq = lane >> 4;

  const int ar = tid >> 2, ac = (tid & 3) * 2;
  const bool avalid = (m0 + ar) < cnt;
  const __bf16* a_src =
      avalid ? (act + (size_t)(obase + m0 + ar) * FFN + ac * 8) : nullptr;

  // B staging: thread -> (n_off via wid-bit1, k range via wid-bit0 and
  // lane-bit5), 16 k-strided dwords. Per instr: 2x128B contiguous segments.
  const int n_off = (wid >> 1) * 32 + (lane & 31);
  const int bk0 = (wid & 1) * 32 + (lane >> 5) * 16;
  const int bc0 = bk0 >> 3;
  const float* b_ptr = w2 + (size_t)e * FFN * HID
                     + (size_t)bk0 * HID + n0 + n_off;

  v4f acc[2][2];
#pragma unroll
  for (int mi = 0; mi < 2; ++mi)
#pragma unroll
    for (int ni = 0; ni < 2; ++ni) {
      v4f z = {0.f, 0.f, 0.f, 0.f};
      acc[mi][ni] = z;
    }

  for (int kt = 0; kt < FFN; kt += 64) {
    // ---- stage A ----
    if (avalid) {
      const v8bf* s = (const v8bf*)(a_src + kt);
      *(v8bf*)&sA[swz(ar, ac)] = s[0];
      *(v8bf*)&sA[swz(ar, ac + 1)] = s[1];
    } else {
      *(v8bf*)&sA[swz(ar, ac)] = zero_v8bf();
      *(v8bf*)&sA[swz(ar, ac + 1)] = zero_v8bf();
    }
    // ---- stage B (transposed, fp32 -> bf16) ----
    {
      const float* src = b_ptr + (size_t)kt * HID;
      float pb[16];
#pragma unroll
      for (int j = 0; j < 16; ++j) pb[j] = src[(size_t)j * HID];
#pragma unroll
      for (int c = 0; c < 2; ++c) {
        v8bf v;
#pragma unroll
        for (int j = 0; j < 8; ++j) v[j] = (__bf16)pb[c * 8 + j];
        *(v8bf*)&sB[swz(n_off, bc0 + c)] = v;
      }
    }
    __syncthreads();

#pragma unroll
    for (int ks = 0; ks < 2; ++ks) {
      v8bf a[2], b[2];
#pragma unroll
      for (int mi = 0; mi < 2; ++mi)
        a[mi] = *(const v8bf*)&sA[swz(wr * 32 + mi * 16 + lrow, ks * 4 + lq)];
#pragma unroll
      for (int ni = 0; ni < 2; ++ni)
        b[ni] = *(const v8bf*)&sB[swz(wf * 32 + ni * 16 + lrow, ks * 4 + lq)];
#pragma unroll
      for (int mi = 0; mi < 2; ++mi)
#pragma unroll
        for (int ni = 0; ni < 2; ++ni)
          acc[mi][ni] = __builtin_amdgcn_mfma_f32_16x16x32_bf16(
              a[mi], b[ni], acc[mi][ni], 0, 0, 0);
    }
    __syncthreads();
  }

  // ---- epilogue: atomicAdd weighted expert output into out ----
#pragma unroll
  for (int mi = 0; mi < 2; ++mi) {
#pragma unroll
    for (int ni = 0; ni < 2; ++ni) {
      const int n = n0 + wf * 32 + ni * 16 + lrow;
#pragma unroll
      for (int r = 0; r < 4; ++r) {
        const int lr = wr * 32 + mi * 16 + lq * 4 + r;
        const int m = m0 + lr;
        if (m < cnt) {
          const int t = sTok[lr];
          atomicAdd(&out[(size_t)t * HID + n], acc[mi][ni][r]);
        }
      }
    }
  }
}

// ---------------------------------------------------------------------------
extern "C" void kernel_launch(void* const* d_in, const int* in_sizes, int n_in,
                              void* d_out, int out_size, void* d_ws, size_t ws_size,
                              hipStream_t stream) {
  const float* hidden = (const float*)d_in[0];
  const float* rw     = (const float*)d_in[1];
  const float* bias   = (const float*)d_in[2];
  const float* w13    = (const float*)d_in[3];
  const float* w2     = (const float*)d_in[4];
  float* out = (float*)d_out;

  char* ws = (char*)d_ws;
  int* counts = (int*)ws;
  int* offsets = (int*)(ws + 64);
  int* pair_token = (int*)(ws + 256);
  float* pair_weight = (float*)(ws + 256 + (size_t)NEXP * TOKENS * 4);
  __bf16* hbf = (__bf16*)(ws + 256 + 2 * (size_t)NEXP * TOKENS * 4);
  __bf16* act = hbf + (size_t)TOKENS * HID;

  hipMemsetAsync(counts, 0, 16 * sizeof(int), stream);
  router_kernel<<<TOKENS, 256, 0, stream>>>(hidden, rw, bias, out, hbf,
                                            counts, pair_token, pair_weight);
  scan_kernel<<<1, 64, 0, stream>>>(counts, offsets);
  // gemm1: 32 ghi x 32 mt x 8 xcd = 8192 blocks (groups = 16e x 16ft)
  gemm1_kernel<<<8192, 256, 0, stream>>>(
      hbf, w13, counts, offsets, pair_token, pair_weight, act);
  // gemm2: 64 ghi x 32 mt x 8 xcd = 16384 blocks (groups = 16e x 32nt)
  gemm2_kernel<<<16384, 256, 0, stream>>>(
      act, w2, counts, offsets, pair_token, out);
}